// Round 12
// baseline (1083.614 us; speedup 1.0000x reference)
//
#include <hip/hip_runtime.h>
#include <hip/hip_bf16.h>
#include <math.h>

typedef unsigned short u16;
typedef __attribute__((ext_vector_type(4))) float f32x4;
typedef __attribute__((ext_vector_type(8))) __bf16 bf16x8;

#define B_    4
#define NQ_   3136
#define C_    512
#define HIMG  56
#define WIMG  56
#define HD_   4096
#define NK_   784
#define NKP_  896

static __device__ __forceinline__ float b2f(u16 u){
  union { unsigned int i; float f; } v; v.i = ((unsigned int)u)<<16; return v.f;
}
static __device__ __forceinline__ u16 f2b(float f){
  union { float f; unsigned int i; } v; v.f = f;
  unsigned int r = v.i + 0x7fffu + ((v.i>>16)&1u);
  return (u16)(r>>16);
}

#define GLD16(gsrc, ldst) __builtin_amdgcn_global_load_lds( \
    (const __attribute__((address_space(1))) void*)(gsrc), \
    (__attribute__((address_space(3))) void*)(ldst), 16, 0, 0)

// ---------------------------------------------------------------------------
// Block-order decodes (XCD = linear_id % 8 round-robin).
// ---------------------------------------------------------------------------
static __device__ __forceinline__ long xcd_rank(long n){
  const long l = blockIdx.x + (long)gridDim.x*(blockIdx.y + (long)gridDim.y*blockIdx.z);
  const long q8 = n>>3, r8 = n&7;
  const long xcd = l&7, idx = l>>3;
  return (xcd<r8 ? xcd*(q8+1) : r8*(q8+1) + (xcd-r8)*q8) + idx;
}
static __device__ __forceinline__ void order_byinner(int &bx, int &by, int &bz){
  const int nx = gridDim.x, ny = gridDim.y, nz = gridDim.z;
  long g = xcd_rank((long)nx*ny*nz);
  by = (int)(g % ny); g /= ny;
  bx = (int)(g % nx);
  bz = (int)(g / nx);
}
static __device__ __forceinline__ void order_panel(int mp, int np, int &bx, int &by){
  const int nx = gridDim.x, ny = gridDim.y;
  int rem = (int)xcd_rank((long)nx*ny);
  int mi = 0, ni = 0;
  for(int p = 0; p < mp*np; p++){
    mi = p/np; ni = p%np;
    const int sx = nx/mp + (mi < nx%mp ? 1 : 0);
    const int sy = ny/np + (ni < ny%np ? 1 : 0);
    const int cnt = sx*sy;
    if(rem < cnt) break;
    rem -= cnt;
  }
  const int sy = ny/np + (ni < ny%np ? 1 : 0);
  const int basex = mi*(nx/mp) + (mi < nx%mp ? mi : nx%mp);
  const int basey = ni*(ny/np) + (ni < ny%np ? ni : ny%np);
  bx = basex + rem / sy;
  by = basey + rem % sy;
}

// ---------------------------------------------------------------------------
// 256x256 8-wave 8-phase bf16 GEMM (m201 template port).
// C[m,n] = (sum_k A[m,k]*B[n,k] + bias1[n]) * hscale * scalePtr[z] (+bias2).
// A:(M,K) stride sA; B:(N,K) stride sB; BK=64, 512 thr = 8 waves 2(M)x4(N),
// wave tile 128x64, per phase 16 MFMA = one C-quadrant (64x32) x K=64.
// LDS 128 KiB: A = 4 half-slots x 16KB @0, B = 4 half-slots x 16KB @64KB.
// Half = 128 rows x 64 K. Tile t uses slots (t&1)*2+{0,1} per operand.
// Phase schedule per tile t (2 barriers each):
//  ph0: rd A(qm0) 8 + B(qn0) 4 b128 | stage B(t+1,1) | bar lgk0 sb prio MFMA(0,0)
//  ph1: rd B(qn1) 4                 | stage A(t+1,1) | ...      MFMA(0,1)
//  ph2: rd A(qm1) 8                 | stage B(t+2,0) | ...      MFMA(1,0)
//  ph3: (regs)                      | stage A(t+2,0) | vmcnt gate; bar; MFMA(1,1)
// Stage targets verified free: other-parity slots at ph0/ph1; same-parity B
// after its ph1 readers, same-parity A after its ph2 readers (2 barriers gap).
// vmcnt gate (once/tile, end of ph3 for next tile): tile t+1's last-staged
// half (A1 @ t.ph1) has exactly 2 halves = 4 loads after it -> vmcnt(4);
// tail (no further stages) -> vmcnt(0). Each wave gates its OWN loads; the
// following barrier publishes arrival to all waves.
// Swizzle st_16x32: lds_byte ^= ((byte>>9)&1)<<5, realized as pre-swizzled
// global source column (gload_lds writes linearly) + XOR'd ds_read address;
// the two XORs cancel (rule 21 both-sides involution).
// Loads NOT masked (caller guarantees over-read slack); stores masked.
// Requires K%64==0, K>=192.
// ---------------------------------------------------------------------------
template<int OUT_F32>
__global__ __launch_bounds__(512)
void gemm8p(const u16* __restrict__ A, const u16* __restrict__ Bm, void* __restrict__ Cm,
            int M, int Ncols, int K, int sA, int sB, int sC, int zdiv,
            long long zA1, long long zA2, long long zB1, long long zB2,
            long long zC1, long long zC2,
            const float* __restrict__ bias1, float hscale,
            const float* __restrict__ scalePtr,
            const float* __restrict__ bias2, int rowsPerB, int b2s,
            int mp, int np)
{
  __shared__ u16 lds[65536];    // 128 KiB
  int bx, by, z;
  if(mp > 0){ order_panel(mp, np, bx, by); z = 0; }
  else      { order_byinner(bx, by, z); }
  const int zq = z / zdiv, zr = z % zdiv;
  const u16* Ab = A  + (long long)zq*zA1 + (long long)zr*zA2;
  const u16* Bb = Bm + (long long)zq*zB1 + (long long)zr*zB2;
  const int m0 = bx*256, n0 = by*256;
  const int t = threadIdx.x, w = t>>6, lane = t&63;
  const int wm = w>>2, wn = w&3;            // 2(M) x 4(N)
  const int l15 = lane & 15;

  // ---- staging source (pre-swizzled column) ----
  // thread t stages dest d = i*8192 + t*16 bytes of a 16KB half:
  // row = i*64 + (t>>3); src col elems = (t&7)*8 ^ ((t>>5)&1)*16.
  const int srow = t>>3;
  const int scol = ((t&7)*8) ^ (((t>>5)&1)*16);
  const u16* aS = Ab + (long long)(m0 + srow)*sA + scol;
  const u16* bS = Bb + (long long)(n0 + srow)*sB + scol;
  const long long sA64 = (long long)64*sA, sA128 = (long long)128*sA;
  const long long sB64 = (long long)64*sB, sB128 = (long long)128*sB;
  const int w512 = w*512;   // wave LDS base (u16): w*1024 bytes

#define STAGE_A(tk, h) do{                                            \
    const u16* s_ = aS + (long long)(h)*sA128 + (long long)(tk)*64;   \
    u16* d_ = lds + ((((tk)&1)*2 + (h))*8192) + w512;                 \
    GLD16(s_,        d_);                                             \
    GLD16(s_ + sA64, d_ + 4096);                                      \
  }while(0)
#define STAGE_B(tk, h) do{                                            \
    const u16* s_ = bS + (long long)(h)*sB128 + (long long)(tk)*64;   \
    u16* d_ = lds + 32768 + ((((tk)&1)*2 + (h))*8192) + w512;         \
    GLD16(s_,        d_);                                             \
    GLD16(s_ + sB64, d_ + 4096);                                      \
  }while(0)

  f32x4 acc[8][4];
#pragma unroll
  for(int i=0;i<8;i++)
#pragma unroll
    for(int j=0;j<4;j++) acc[i][j] = (f32x4)(0.0f);

  const char* ldsc = (const char*)lds;
  // ds_read byte offset inside a half-slot: row*128 + (k32*64 + (lane>>4)*16)^swz
  const int swz5 = ((lane>>2)&1)<<5;       // == ((row>>2)&1)<<5 for our rows
  const int k0 = (0*64 + ((lane>>4)<<4)) ^ swz5;
  const int k1 = (1*64 + ((lane>>4)<<4)) ^ swz5;
  const int aHalfSel = wm;                 // wave's A-half
  const int bHalfSel = wn>>1;              // wave's B-half
  const int bRow0 = (wn&1)*64;             // B local row base inside its half

  bf16x8 af[4][2], bf[2][2][2];

#define RD_A(qm) do{                                                        \
    const int base_ = aSlot + ((qm)*64 + l15)*128;                          \
    _Pragma("unroll")                                                       \
    for(int fr=0; fr<4; fr++){                                              \
      af[fr][0] = *(const bf16x8*)(ldsc + base_ + fr*16*128 + k0);          \
      af[fr][1] = *(const bf16x8*)(ldsc + base_ + fr*16*128 + k1);          \
    }                                                                       \
  }while(0)
#define RD_B(qn) do{                                                        \
    const int base_ = bSlot + (bRow0 + (qn)*32 + l15)*128;                  \
    _Pragma("unroll")                                                       \
    for(int fn=0; fn<2; fn++){                                              \
      bf[qn][fn][0] = *(const bf16x8*)(ldsc + base_ + fn*16*128 + k0);      \
      bf[qn][fn][1] = *(const bf16x8*)(ldsc + base_ + fn*16*128 + k1);      \
    }                                                                       \
  }while(0)
#define MM(qm,qn) do{                                                       \
    _Pragma("unroll")                                                       \
    for(int fr=0; fr<4; fr++)                                               \
      _Pragma("unroll")                                                     \
      for(int fn=0; fn<2; fn++){                                            \
        f32x4 t_ = acc[(qm)*4+fr][(qn)*2+fn];                               \
        t_ = __builtin_amdgcn_mfma_f32_16x16x32_bf16(af[fr][0], bf[qn][fn][0], t_, 0,0,0); \
        t_ = __builtin_amdgcn_mfma_f32_16x16x32_bf16(af[fr][1], bf[qn][fn][1], t_, 0,0,0); \
        acc[(qm)*4+fr][(qn)*2+fn] = t_;                                     \
      }                                                                     \
  }while(0)
#define BAR()   asm volatile("s_barrier" ::: "memory")
#define LGK0()  do{ asm volatile("s_waitcnt lgkmcnt(0)" ::: "memory"); \
                    __builtin_amdgcn_sched_barrier(0); }while(0)

  const int T = K >> 6;
  // prologue: t0 all 4 halves FIRST, then t1's B0,A0 (gate math depends on order)
  STAGE_A(0,0); STAGE_A(0,1); STAGE_B(0,0); STAGE_B(0,1);
  STAGE_B(1,0); STAGE_A(1,0);
  asm volatile("s_waitcnt vmcnt(4)" ::: "memory");   // t0's 8 loads arrived
  BAR();

  for(int tk=0; tk<T; tk++){
    const int aSlot = ((tk&1)*2 + aHalfSel)*16384;
    const int bSlot = 65536 + ((tk&1)*2 + bHalfSel)*16384;
    // ---- ph0: A(qm0)+B(qn0); stage B(t+1,1) ----
    RD_A(0); RD_B(0);
    if(tk+1 < T) STAGE_B(tk+1, 1);
    BAR(); LGK0();
    __builtin_amdgcn_s_setprio(1); MM(0,0); __builtin_amdgcn_s_setprio(0);
    BAR();
    // ---- ph1: B(qn1); stage A(t+1,1) ----
    RD_B(1);
    if(tk+1 < T) STAGE_A(tk+1, 1);
    BAR(); LGK0();
    __builtin_amdgcn_s_setprio(1); MM(0,1); __builtin_amdgcn_s_setprio(0);
    BAR();
    // ---- ph2: A(qm1); stage B(t+2,0) ----
    RD_A(1);
    if(tk+2 < T) STAGE_B(tk+2, 0);
    BAR(); LGK0();
    __builtin_amdgcn_s_setprio(1); MM(1,0); __builtin_amdgcn_s_setprio(0);
    BAR();
    // ---- ph3: regs only; stage A(t+2,0); vmcnt gate for next tile ----
    if(tk+2 < T) STAGE_A(tk+2, 0);
    if(tk+1 < T){
      if(tk+2 < T) asm volatile("s_waitcnt vmcnt(4)" ::: "memory");
      else         asm volatile("s_waitcnt vmcnt(0)" ::: "memory");
    }
    BAR();
    __builtin_amdgcn_s_setprio(1); MM(1,1); __builtin_amdgcn_s_setprio(0);
    BAR();
  }
#undef RD_A
#undef RD_B
#undef MM
#undef STAGE_A
#undef STAGE_B

  const float dsc = scalePtr ? scalePtr[z] : 1.0f;
  const long long cBase = (long long)zq*zC1 + (long long)zr*zC2;
  const int r4 = (lane>>4)*4;
#pragma unroll
  for(int mf=0; mf<8; mf++){
    const int row0 = m0 + wm*128 + mf*16 + r4;
#pragma unroll
    for(int nf=0; nf<4; nf++){
      const int col = n0 + wn*64 + nf*16 + l15;
      if(col < Ncols){
#pragma unroll
        for(int r=0;r<4;r++){
          const int row = row0 + r;
          if(row < M){
            float v = acc[mf][nf][r];
            if(bias1) v += bias1[col];
            v *= hscale * dsc;
            if(bias2) v += bias2[(row/rowsPerB)*b2s + col];
            if(OUT_F32) ((float*)Cm)[cBase + (long long)row*sC + col] = v;
            else        ((u16*) Cm)[cBase + (long long)row*sC + col] = f2b(v);
          }
        }
      }
    }
  }
}

// ---------------------------------------------------------------------------
// 256x128 4-wave 2-phase GEMM (r11 v7) kept for the small KV-proj grid.
// ---------------------------------------------------------------------------
template<int OUT_F32>
__global__ __launch_bounds__(256, 2)
void gemm128(const u16* __restrict__ A, const u16* __restrict__ Bm, void* __restrict__ Cm,
             int M, int Ncols, int K, int sA, int sB, int sC, int zdiv,
             long long zA1, long long zA2, long long zB1, long long zB2,
             long long zC1, long long zC2,
             const float* __restrict__ bias1, float hscale,
             const float* __restrict__ scalePtr,
             const float* __restrict__ bias2, int rowsPerB, int b2s,
             int mp, int np)
{
  __shared__ u16 lds[36864];
  int bx, by, z;
  if(mp > 0){ order_panel(mp, np, bx, by); z = 0; }
  else      { order_byinner(bx, by, z); }
  const int zq = z / zdiv, zr = z % zdiv;
  const u16* Ab = A  + (long long)zq*zA1 + (long long)zr*zA2;
  const u16* Bb = Bm + (long long)zq*zB1 + (long long)zr*zB2;
  const int m0 = bx*256, n0 = by*128;
  const int t = threadIdx.x, w = t>>6, lane = t&63;
  const int wm = w>>1, wn = w&1;
  const int l15 = lane & 15;

  const int srow = t>>2;
  const int scol = (((t&3) ^ ((srow>>1)&3)) << 3);
  const u16* aS = Ab + (long long)(m0 + srow)*sA + scol;
  const u16* bS = Bb + (long long)(n0 + srow)*sB + scol;
  const long long sA64 = (long long)64*sA, sB64 = (long long)64*sB;
  const int w512 = w*512;

#define STAGE(jt, buf) do{                                        \
    const u16* a0_ = aS + (long long)(jt)*32;                     \
    const u16* b0_ = bS + (long long)(jt)*32;                     \
    u16* la_ = lds + (buf)*8192 + w512;                           \
    u16* lb_ = lds + 24576 + (buf)*4096 + w512;                   \
    GLD16(a0_,          la_);                                     \
    GLD16(a0_ +   sA64, la_ + 2048);                              \
    GLD16(a0_ + 2*sA64, la_ + 4096);                              \
    GLD16(a0_ + 3*sA64, la_ + 6144);                              \
    GLD16(b0_,          lb_);                                     \
    GLD16(b0_ +   sB64, lb_ + 2048);                              \
  }while(0)

  f32x4 acc[8][4];
#pragma unroll
  for(int i=0;i<8;i++)
#pragma unroll
    for(int j=0;j<4;j++) acc[i][j] = (f32x4)(0.0f);

  const char* ldsc = (const char*)lds;
  const int ck = (((lane>>4) ^ ((lane>>1)&3)) << 4);
  const int aRowB = (wm*128 + l15) * 64;
  const int bRowB = (wn*64  + l15) * 64;

  const int T = K >> 5;
  STAGE(0, 0);
  STAGE(1, 1);

  int buf = 0;
  for(int j=0; j<T; j++){
    if(j == T-1) asm volatile("s_waitcnt vmcnt(0)" ::: "memory");
    else         asm volatile("s_waitcnt vmcnt(6)" ::: "memory");
    asm volatile("s_barrier" ::: "memory");

    const int aBuf = buf*16384 + aRowB;
    const int bBuf = 49152 + buf*8192 + bRowB;
    bf16x8 af[8], bfv[4];
#pragma unroll
    for(int fr=0; fr<8; fr++) af[fr]  = *(const bf16x8*)(ldsc + aBuf + fr*1024 + ck);
#pragma unroll
    for(int fn=0; fn<4; fn++) bfv[fn] = *(const bf16x8*)(ldsc + bBuf + fn*1024 + ck);
    {
      const int nbuf = (buf+2 >= 3) ? buf-1 : buf+2;
      if(j+2 < T) STAGE(j+2, nbuf);
    }
    __builtin_amdgcn_s_setprio(1);
#pragma unroll
    for(int fr=0; fr<8; fr++)
#pragma unroll
      for(int fn=0; fn<4; fn++)
        acc[fr][fn] = __builtin_amdgcn_mfma_f32_16x16x32_bf16(af[fr], bfv[fn], acc[fr][fn], 0,0,0);
    __builtin_amdgcn_s_setprio(0);
    buf = (buf+1 >= 3) ? 0 : buf+1;
  }
#undef STAGE

  const float dsc = scalePtr ? scalePtr[z] : 1.0f;
  const long long cBase = (long long)zq*zC1 + (long long)zr*zC2;
  const int r4 = (lane>>4)*4;
#pragma unroll
  for(int mf=0; mf<8; mf++){
    const int row0 = m0 + wm*128 + mf*16 + r4;
#pragma unroll
    for(int nf=0; nf<4; nf++){
      const int col = n0 + wn*64 + nf*16 + l15;
      if(col < Ncols){
#pragma unroll
        for(int r=0;r<4;r++){
          const int row = row0 + r;
          if(row < M){
            float v = acc[mf][nf][r];
            if(bias1) v += bias1[col];
            v *= hscale * dsc;
            if(bias2) v += bias2[(row/rowsPerB)*b2s + col];
            if(OUT_F32) ((float*)Cm)[cBase + (long long)row*sC + col] = v;
            else        ((u16*) Cm)[cBase + (long long)row*sC + col] = f2b(v);
          }
        }
      }
    }
  }
}

// f32 (K,N) weight -> bf16 (N,K) transpose
__global__ __launch_bounds__(256)
void wt_kernel(const float* __restrict__ W, u16* __restrict__ Wt, int K, int N){
  __shared__ float tile[32][33];
  const int n0 = blockIdx.x*32, k0 = blockIdx.y*32;
  const int t = threadIdx.x, tr = t>>5, tc = t&31;
#pragma unroll
  for(int i=0;i<4;i++)
    tile[tr+i*8][tc] = W[(long long)(k0+tr+i*8)*N + n0+tc];
  __syncthreads();
#pragma unroll
  for(int i=0;i<4;i++)
    Wt[(long long)(n0+tr+i*8)*K + k0+tc] = f2b(tile[tc][tr+i*8]);
}

__global__ __launch_bounds__(256)
void cvt_bf16(const float* __restrict__ in, u16* __restrict__ outp, long long n){
  long long i = ((long long)blockIdx.x*256 + threadIdx.x)*4;
  if(i+3 < n){
    float4 v = *(const float4*)(in+i);
    ushort4 o; o.x=f2b(v.x); o.y=f2b(v.y); o.z=f2b(v.z); o.w=f2b(v.w);
    *(ushort4*)(outp+i) = o;
  }
}

// depthwise 3x3 stride-2 SAME conv (pad lo=0,hi=1) + bias + LayerNorm -> bf16
__global__ __launch_bounds__(256)
void conv_ln(const float* __restrict__ q, const float* __restrict__ ker,
             const float* __restrict__ cbias, const float* __restrict__ gamma,
             const float* __restrict__ beta, u16* __restrict__ xo)
{
  const int p = blockIdx.x;
  const int b = p / 784, pix = p % 784;
  const int oy = pix / 28, ox = pix % 28;
  const int t = threadIdx.x;
  __shared__ float red[256];
  float v[2];
#pragma unroll
  for(int e=0;e<2;e++){
    const int c = t + e*256;
    float acc = cbias[c];
    for(int ky=0;ky<3;ky++){
      const int y = oy*2 + ky;
      if(y >= HIMG) continue;
      for(int kx=0;kx<3;kx++){
        const int x = ox*2 + kx;
        if(x >= WIMG) continue;
        acc += q[(((long long)b*HIMG + y)*WIMG + x)*C_ + c] * ker[(ky*3+kx)*C_ + c];
      }
    }
    v[e] = acc;
  }
  red[t]=v[0]+v[1]; __syncthreads();
  for(int st=128; st>0; st>>=1){ if(t<st) red[t]+=red[t+st]; __syncthreads(); }
  const float mu = red[0] * (1.0f/C_);
  __syncthreads();
  const float d0=v[0]-mu, d1=v[1]-mu;
  red[t]=d0*d0+d1*d1; __syncthreads();
  for(int st=128; st>0; st>>=1){ if(t<st) red[t]+=red[t+st]; __syncthreads(); }
  const float rs = rsqrtf(red[0]*(1.0f/C_) + 1e-3f);
  const long long ob = (long long)p*C_;
#pragma unroll
  for(int e=0;e<2;e++){
    const int c = t+e*256;
    xo[ob+c] = f2b((v[e]-mu)*rs*gamma[c] + beta[c]);
  }
}

// per-batch: V part of KV_b (784 x 4096, row stride sV) -> Vt_b (4096,896), k zero-padded
__global__ __launch_bounds__(256)
void vt_kernel(const u16* __restrict__ Vf_b, u16* __restrict__ Vt_b, int sV){
  __shared__ u16 tile[32][33];
  const int k0 = blockIdx.x*32, d0 = blockIdx.y*32;
  const int t = threadIdx.x, tr = t>>5, tc = t&31;
#pragma unroll
  for(int i=0;i<4;i++){
    const int k = k0+tr+i*8;
    tile[tr+i*8][tc] = (k < NK_) ? Vf_b[(long long)k*sV + d0+tc] : (u16)0;
  }
  __syncthreads();
#pragma unroll
  for(int i=0;i<4;i++)
    Vt_b[(long long)(d0+tr+i*8)*NKP_ + k0+tc] = tile[tc][tr+i*8];
}

// ---------------------------------------------------------------------------
// Wave-parallel mix+softmax: one block (512 thr = 8 waves) per q-row.
// Unique-slot partial sums. Zeroes pad cols 784..895.
// ---------------------------------------------------------------------------
__global__ __launch_bounds__(512)
void mix_softmax(u16* __restrict__ S_b, const float* __restrict__ tw,
                 float* __restrict__ partial_b)
{
  const int qi = blockIdx.x;
  const int t = threadIdx.x;
  const int wave = t >> 6, lane = t & 63;
  __shared__ float sv[8*NK_];
  const long long rowstr = (long long)NQ_*NKP_;
  const long long base = (long long)qi*NKP_;

  for(int idx = t; idx < 8*196; idx += 512){
    const int h = idx / 196, c4 = idx % 196;
    ushort4 u4 = *(const ushort4*)(S_b + base + h*rowstr + c4*4);
    float* d = sv + h*NK_ + c4*4;
    d[0]=b2f(u4.x); d[1]=b2f(u4.y); d[2]=b2f(u4.z); d[3]=b2f(u4.w);
  }
  __syncthreads();

  const int g = wave;
  float wgt[8];
#pragma unroll
  for(int h=0;h<8;h++) wgt[h] = tw[h*8+g];

  float xs[13];
  float lmax = -1e30f;
#pragma unroll
  for(int j=0;j<13;j++){
    const int k = j*64 + lane;
    if(k < NK_){
      float x = 0.f;
#pragma unroll
      for(int h=0;h<8;h++) x += wgt[h]*sv[h*NK_+k];
      xs[j] = x;
      lmax = fmaxf(lmax, x);
    } else xs[j] = -1e30f;
  }
#pragma unroll
  for(int off=32; off>=1; off>>=1) lmax = fmaxf(lmax, __shfl_xor(lmax, off));

  float lsum = 0.f;
#pragma unroll
  for(int j=0;j<13;j++){
    const int k = j*64 + lane;
    if(k < NK_){
      const float e = __expf(xs[j] - lmax);
      xs[j] = e; lsum += e;
    }
  }
#pragma unroll
  for(int off=32; off>=1; off>>=1) lsum += __shfl_xor(lsum, off);
  const float inv = 1.0f/lsum;

  u16* dst = S_b + base + g*rowstr;
  float lss = 0.f;
#pragma unroll
  for(int j=0;j<13;j++){
    const int k = j*64 + lane;
    if(k < NK_){
      const float dev = xs[j]*inv - (1.0f/NK_);
      dst[k] = f2b(dev);
      lss += dev*dev;
    }
  }
  for(int k = NK_ + lane; k < NKP_; k += 64) dst[k] = 0;
#pragma unroll
  for(int off=32; off>=1; off>>=1) lss += __shfl_xor(lss, off);
  if(lane==0) partial_b[g*NQ_ + qi] = lss;
}

// column sums of V, k-split into 8 chunks of 98 -> part[kc][hd]
__global__ __launch_bounds__(256)
void colsum_v(const u16* __restrict__ Vf_b, float* __restrict__ part, int sV){
  const int hd = blockIdx.x*256 + threadIdx.x;
  const int kc = blockIdx.y;
  const u16* p = Vf_b + (long long)kc*98*sV + hd;
  float s=0.f;
  for(int k=0;k<98;k++) s += b2f(p[(long long)k*sV]);
  part[(long long)kc*HD_ + hd] = s;
}

__global__ __launch_bounds__(256)
void finalize_stats(const float* __restrict__ partial_b, const float* __restrict__ bng_b,
                    const float* __restrict__ bnb_b, float* __restrict__ a_b,
                    float* __restrict__ c_b){
  const int g = blockIdx.x;
  const int t = threadIdx.x;
  __shared__ float red[4];
  float s = 0.f;
  for(int i=t; i<NQ_; i+=256) s += partial_b[g*NQ_ + i];
#pragma unroll
  for(int off=32; off>=1; off>>=1) s += __shfl_xor(s, off);
  if((t&63)==0) red[t>>6] = s;
  __syncthreads();
  if(t==0){
    const float tot = red[0]+red[1]+red[2]+red[3];
    const float s2 = tot * (1.0f/((float)NQ_*(float)NK_));
    a_b[g] = bng_b[g]*rsqrtf(s2 + 1e-3f);
    c_b[g] = bnb_b[g];
  }
}

// corr_b[n] = sum_g c_b[g] * (colsumV_b[g*512:(g+1)*512] . Wo_g[:,n]); colsum k-split
__global__ __launch_bounds__(256)
void corr_kernel(const float* __restrict__ part, const u16* __restrict__ Wot,
                 const float* __restrict__ c_b, float* __restrict__ corr_b){
  const int n = blockIdx.x, t = threadIdx.x;
  __shared__ float red[256];
  float s = 0.f;
  for(int hd=t; hd<HD_; hd+=256){
    float cs = 0.f;
#pragma unroll
    for(int kc=0; kc<8; kc++) cs += part[(long long)kc*HD_ + hd];
    s += c_b[hd>>9] * cs * b2f(Wot[(long long)n*HD_+hd]);
  }
  red[t]=s; __syncthreads();
  for(int st=128; st>0; st>>=1){ if(t<st) red[t]+=red[t+st]; __syncthreads(); }
  if(t==0) corr_b[n]=red[0];
}

// ---------------------------------------------------------------------------
extern "C" void kernel_launch(void* const* d_in, const int* in_sizes, int n_in,
                              void* d_out, int out_size, void* d_ws, size_t ws_size,
                              hipStream_t stream)
{
  (void)in_sizes; (void)n_in; (void)out_size;
  const float* queries = (const float*)d_in[0];
  const float* Wq  = (const float*)d_in[3];
  const float* bq  = (const float*)d_in[4];
  const float* Wk  = (const float*)d_in[5];
  const float* bk  = (const float*)d_in[6];
  const float* Wv  = (const float*)d_in[7];
  const float* bv  = (const float*)d_in[8];
  const float* Wo  = (const float*)d_in[9];
  const float* bo  = (const float*)d_in[10];
  const float* srk = (const float*)d_in[11];
  const float* srb = (const float*)d_in[12];
  const float* lng = (const float*)d_in[13];
  const float* lnb = (const float*)d_in[14];
  const float* tw  = (const float*)d_in[15];
  const float* bng = (const float*)d_in[17];
  const float* bnb = (const float*)d_in[18];
  float* out = (float*)d_out;
  const float QSC = 0.04419417382415922f;   // 1/sqrt(512)

  char* w = (char*)d_ws;
  size_t off = 0;
  auto alloc = [&](size_t bytes)->char*{
    char* p = w + off; off += (bytes + 255) & ~(size_t)255; return p;
  };

  const bool tierA = (ws_size >= (size_t)210*1024*1024);

  u16* Wqt = (u16*)alloc((size_t)HD_*C_*2);
  u16* Wkt = (u16*)alloc((size_t)HD_*C_*2);   // Wvt follows contiguously
  u16* Wvt = (u16*)alloc((size_t)HD_*C_*2);
  u16* Wot = (u16*)alloc((size_t)C_*HD_*2);
  u16* x   = (u16*)alloc((size_t)B_*NK_*C_*2 + 262144);
  float* bkv = (float*)alloc((size_t)2*HD_*4);
  u16* Qin;
  u16* QfU;
  if(tierA){
    Qin = (u16*)alloc((size_t)B_*NQ_*C_*2);
    QfU = (u16*)alloc((size_t)B_*NQ_*HD_*2 + 2097152);      // +2M: score A over-read
  } else {
    Qin = (u16*)alloc((size_t)NQ_*C_*2 + 262144);
    QfU = (u16*)alloc((size_t)NQ_*HD_*2 + 2097152);
  }
  u16* KV_b = (u16*)alloc((size_t)NK_*2*HD_*2 + 4194304);   // +4M: score B over-read (240 rows)
  u16* Vt_b = (u16*)alloc((size_t)HD_*NKP_*2);
  u16* S_b  = (u16*)alloc((size_t)8*NQ_*NKP_*2 + 524288);   // +512K: PV A over-read
  float* colsum  = (float*)alloc((size_t)8*HD_*4);
  float* partial = (float*)alloc((size_t)8*NQ_*4);
  float* aArr    = (float*)alloc(256);
  float* cArr    = (float*)alloc(256);
  float* corrB   = (float*)alloc((size_t)B_*C_*4);

  // ---- weight prep + conv+LN ----
  wt_kernel<<<dim3(128,16), 256, 0, stream>>>(Wq, Wqt, 512, 4096);
  wt_kernel<<<dim3(128,16), 256, 0, stream>>>(Wk, Wkt, 512, 4096);
  wt_kernel<<<dim3(128,16), 256, 0, stream>>>(Wv, Wvt, 512, 4096);
  wt_kernel<<<dim3(16,128), 256, 0, stream>>>(Wo, Wot, 4096, 512);
  conv_ln<<<B_*NK_, 256, 0, stream>>>(queries, srk, srb, lng, lnb, x);
  hipMemcpyAsync(bkv,      bk, HD_*4, hipMemcpyDeviceToDevice, stream);
  hipMemcpyAsync(bkv+HD_,  bv, HD_*4, hipMemcpyDeviceToDevice, stream);

  if(tierA){
    cvt_bf16<<<6272, 256, 0, stream>>>(queries, Qin, (long long)B_*NQ_*C_);
    // Qf = (queries@Wq + bq)/sqrt(512): 8-phase template, panel order 4x2
    gemm8p<0><<<dim3(49,16,1),512,0,stream>>>(Qin, Wqt, QfU, B_*NQ_, 4096, 512,
        512, 512, HD_, 1, 0,0,0,0,0,0, bq, QSC, nullptr, nullptr, 1, 0, 4, 2);
  }

  for(int b=0; b<B_; b++){
    u16* Qf_b = tierA ? (QfU + (size_t)b*NQ_*HD_) : QfU;
    if(!tierA){
      cvt_bf16<<<1568, 256, 0, stream>>>(queries + (size_t)b*NQ_*C_, Qin, (long long)NQ_*C_);
      gemm8p<0><<<dim3(13,16,1),512,0,stream>>>(Qin, Wqt, Qf_b, NQ_, 4096, 512,
          512, 512, HD_, 1, 0,0,0,0,0,0, bq, QSC, nullptr, nullptr, 1, 0, 4, 2);
    }
    const u16* x_b = x + (size_t)b*NK_*C_;
    // combined K|V projection (small grid -> 2-phase kernel)
    gemm128<0><<<dim3(4,64,1),256,0,stream>>>(x_b, Wkt, KV_b, NK_, 2*HD_, 512,
        512, 512, 2*HD_, 1, 0,0,0,0,0,0, bkv, 1.0f, nullptr, nullptr, 1, 0, 0, 0);
    vt_kernel<<<dim3(28,128),256,0,stream>>>(KV_b + HD_, Vt_b, 2*HD_);
    colsum_v<<<dim3(16,8),256,0,stream>>>(KV_b + HD_, colsum, 2*HD_);
    // per-head scores: S_b[z] = Qf_b[:, z*512:+512] @ K_b[:, z*512:+512]^T
    gemm8p<0><<<dim3(13,4,8),512,0,stream>>>(Qf_b, KV_b, S_b, NQ_, NKP_, 512,
        HD_, 2*HD_, NKP_, 8, 0, 512, 0, 512, 0, (long long)NQ_*NKP_,
        nullptr, 1.0f, nullptr, nullptr, 1, 0, 0, 0);
    mix_softmax<<<NQ_, 512, 0, stream>>>(S_b, tw, partial);
    finalize_stats<<<8,256,0,stream>>>(partial, bng + b*8, bnb + b*8, aArr + b*8, cArr + b*8);
    corr_kernel<<<512,256,0,stream>>>(colsum, Wot, cArr + b*8, corrB + b*C_);
    // U_b[:, z*512+d] = a[b,z] * (P~_z @ V_z)   (K=896 -> T=14 tiles)
    gemm8p<0><<<dim3(13,2,8),512,0,stream>>>(S_b, Vt_b, Qf_b, NQ_, 512, NKP_,
        NKP_, NKP_, HD_, 8, 0, (long long)NQ_*NKP_, 0, (long long)512*NKP_, 0, 512,
        nullptr, 1.0f, aArr + b*8, nullptr, 1, 0, 0, 0);
    if(!tierA){
      gemm8p<1><<<dim3(13,2,1),512,0,stream>>>(Qf_b, Wot, out + (size_t)b*NQ_*C_,
          NQ_, 512, HD_, HD_, HD_, C_,
          1, 0,0,0,0,0,0, bo, 1.0f, nullptr, corrB + b*C_, NQ_, C_, 0, 0);
    }
  }

  if(tierA){
    // out = U @ Wo + bo + corr[b,:]  (K=4096 -> T=64: deep pipeline)
    gemm8p<1><<<dim3(49,2,1),512,0,stream>>>(QfU, Wot, out, B_*NQ_, 512, HD_,
        HD_, HD_, C_, 1, 0,0,0,0,0,0, bo, 1.0f, nullptr, corrB, NQ_, C_, 0, 0);
  }
}

// Round 13
// 1048.055 us; speedup vs baseline: 1.0339x; 1.0339x over previous
//
#include <hip/hip_runtime.h>
#include <hip/hip_bf16.h>
#include <math.h>

typedef unsigned short u16;
typedef __attribute__((ext_vector_type(4))) float f32x4;
typedef __attribute__((ext_vector_type(8))) __bf16 bf16x8;

#define B_    4
#define NQ_   3136
#define C_    512
#define HIMG  56
#define WIMG  56
#define HD_   4096
#define NK_   784
#define NKP_  896

static __device__ __forceinline__ float b2f(u16 u){
  union { unsigned int i; float f; } v; v.i = ((unsigned int)u)<<16; return v.f;
}
static __device__ __forceinline__ u16 f2b(float f){
  union { float f; unsigned int i; } v; v.f = f;
  unsigned int r = v.i + 0x7fffu + ((v.i>>16)&1u);
  return (u16)(r>>16);
}

#define GLD16(gsrc, ldst) __builtin_amdgcn_global_load_lds( \
    (const __attribute__((address_space(1))) void*)(gsrc), \
    (__attribute__((address_space(3))) void*)(ldst), 16, 0, 0)

// ---------------------------------------------------------------------------
// Block-order decodes (XCD = linear_id % 8 round-robin).
// ---------------------------------------------------------------------------
static __device__ __forceinline__ long xcd_rank(long n){
  const long l = blockIdx.x + (long)gridDim.x*(blockIdx.y + (long)gridDim.y*blockIdx.z);
  const long q8 = n>>3, r8 = n&7;
  const long xcd = l&7, idx = l>>3;
  return (xcd<r8 ? xcd*(q8+1) : r8*(q8+1) + (xcd-r8)*q8) + idx;
}
static __device__ __forceinline__ void order_byinner(int &bx, int &by, int &bz){
  const int nx = gridDim.x, ny = gridDim.y, nz = gridDim.z;
  long g = xcd_rank((long)nx*ny*nz);
  by = (int)(g % ny); g /= ny;
  bx = (int)(g % nx);
  bz = (int)(g / nx);
}
static __device__ __forceinline__ void order_panel(int mp, int np, int &bx, int &by){
  const int nx = gridDim.x, ny = gridDim.y;
  int rem = (int)xcd_rank((long)nx*ny);
  int mi = 0, ni = 0;
  for(int p = 0; p < mp*np; p++){
    mi = p/np; ni = p%np;
    const int sx = nx/mp + (mi < nx%mp ? 1 : 0);
    const int sy = ny/np + (ni < ny%np ? 1 : 0);
    const int cnt = sx*sy;
    if(rem < cnt) break;
    rem -= cnt;
  }
  const int sy = ny/np + (ni < ny%np ? 1 : 0);
  const int basex = mi*(nx/mp) + (mi < nx%mp ? mi : nx%mp);
  const int basey = ni*(ny/np) + (ni < ny%np ? ni : ny%np);
  bx = basex + rem / sy;
  by = basey + rem % sy;
}

// ---------------------------------------------------------------------------
// 256x256 8-wave 8-phase bf16 GEMM (m201 template port), swizzle FIXED (r13):
// chunk' = chunk ^ (row&7) on 16B chunks within each 128B row — verified
// 2 lanes/bank (free) for every fragment read; r12's single-bit variant was
// an 8-way conflict (4.8M SQ_LDS_BANK_CONFLICT -> regression).
// C[m,n] = (sum_k A[m,k]*B[n,k] + bias1[n]) * hscale * scalePtr[z] (+bias2).
// A:(M,K) stride sA; B:(N,K) stride sB; BK=64, 512 thr = 8 waves 2(M)x4(N),
// wave tile 128x64, per phase 16 MFMA = one C-quadrant (64x32) x K=64.
// LDS 128 KiB: A = 4 half-slots x 16KB @0, B = 4 half-slots x 16KB @64KB.
// Half = 128 rows x 64 K. Tile t uses slots (t&1)*2+{0,1} per operand.
// Phases per tile (2 barriers each): see r12 header; vmcnt(4) gate once/tile.
// Write side: thread t stages dest row (t>>3)(+64), chunk t&7 -> source col
// elems ((t&7)^((t>>3)&7))*8.  Read side: k-chunk (k32*4+(lane>>4)) ^ (lane&7).
// Loads NOT masked (caller guarantees over-read slack); stores masked.
// Requires K%64==0, K>=192.
// ---------------------------------------------------------------------------
template<int OUT_F32>
__global__ __launch_bounds__(512)
void gemm8p(const u16* __restrict__ A, const u16* __restrict__ Bm, void* __restrict__ Cm,
            int M, int Ncols, int K, int sA, int sB, int sC, int zdiv,
            long long zA1, long long zA2, long long zB1, long long zB2,
            long long zC1, long long zC2,
            const float* __restrict__ bias1, float hscale,
            const float* __restrict__ scalePtr,
            const float* __restrict__ bias2, int rowsPerB, int b2s,
            int mp, int np)
{
  __shared__ u16 lds[65536];    // 128 KiB
  int bx, by, z;
  if(mp > 0){ order_panel(mp, np, bx, by); z = 0; }
  else      { order_byinner(bx, by, z); }
  const int zq = z / zdiv, zr = z % zdiv;
  const u16* Ab = A  + (long long)zq*zA1 + (long long)zr*zA2;
  const u16* Bb = Bm + (long long)zq*zB1 + (long long)zr*zB2;
  const int m0 = bx*256, n0 = by*256;
  const int t = threadIdx.x, w = t>>6, lane = t&63;
  const int wm = w>>2, wn = w&3;            // 2(M) x 4(N)
  const int l15 = lane & 15;

  // staging source (pre-swizzled column): dest row (t>>3), chunk (t&7)
  const int srow = t>>3;
  const int scol = ((t&7) ^ ((t>>3)&7)) * 8;
  const u16* aS = Ab + (long long)(m0 + srow)*sA + scol;
  const u16* bS = Bb + (long long)(n0 + srow)*sB + scol;
  const long long sA64 = (long long)64*sA, sA128 = (long long)128*sA;
  const long long sB64 = (long long)64*sB, sB128 = (long long)128*sB;
  const int w512 = w*512;   // wave LDS base (u16): w*1024 bytes

#define STAGE_A(tk, h) do{                                            \
    const u16* s_ = aS + (long long)(h)*sA128 + (long long)(tk)*64;   \
    u16* d_ = lds + ((((tk)&1)*2 + (h))*8192) + w512;                 \
    GLD16(s_,        d_);                                             \
    GLD16(s_ + sA64, d_ + 4096);                                      \
  }while(0)
#define STAGE_B(tk, h) do{                                            \
    const u16* s_ = bS + (long long)(h)*sB128 + (long long)(tk)*64;   \
    u16* d_ = lds + 32768 + ((((tk)&1)*2 + (h))*8192) + w512;         \
    GLD16(s_,        d_);                                             \
    GLD16(s_ + sB64, d_ + 4096);                                      \
  }while(0)

  f32x4 acc[8][4];
#pragma unroll
  for(int i=0;i<8;i++)
#pragma unroll
    for(int j=0;j<4;j++) acc[i][j] = (f32x4)(0.0f);

  const char* ldsc = (const char*)lds;
  // fragment k-chunk XOR row&7 (row&7 == lane&7 for all our fragment rows)
  const int k0 = (((lane>>4)    ) ^ (lane&7)) << 4;
  const int k1 = ((4 + (lane>>4)) ^ (lane&7)) << 4;
  const int aHalfSel = wm;                 // wave's A-half
  const int bHalfSel = wn>>1;              // wave's B-half
  const int bRow0 = (wn&1)*64;             // B local row base inside its half

  bf16x8 af[4][2], bf[2][2][2];

#define RD_A(qm) do{                                                        \
    const int base_ = aSlot + ((qm)*64 + l15)*128;                          \
    _Pragma("unroll")                                                       \
    for(int fr=0; fr<4; fr++){                                              \
      af[fr][0] = *(const bf16x8*)(ldsc + base_ + fr*16*128 + k0);          \
      af[fr][1] = *(const bf16x8*)(ldsc + base_ + fr*16*128 + k1);          \
    }                                                                       \
  }while(0)
#define RD_B(qn) do{                                                        \
    const int base_ = bSlot + (bRow0 + (qn)*32 + l15)*128;                  \
    _Pragma("unroll")                                                       \
    for(int fn=0; fn<2; fn++){                                              \
      bf[qn][fn][0] = *(const bf16x8*)(ldsc + base_ + fn*16*128 + k0);      \
      bf[qn][fn][1] = *(const bf16x8*)(ldsc + base_ + fn*16*128 + k1);      \
    }                                                                       \
  }while(0)
#define MM(qm,qn) do{                                                       \
    _Pragma("unroll")                                                       \
    for(int fr=0; fr<4; fr++)                                               \
      _Pragma("unroll")                                                     \
      for(int fn=0; fn<2; fn++){                                            \
        f32x4 t_ = acc[(qm)*4+fr][(qn)*2+fn];                               \
        t_ = __builtin_amdgcn_mfma_f32_16x16x32_bf16(af[fr][0], bf[qn][fn][0], t_, 0,0,0); \
        t_ = __builtin_amdgcn_mfma_f32_16x16x32_bf16(af[fr][1], bf[qn][fn][1], t_, 0,0,0); \
        acc[(qm)*4+fr][(qn)*2+fn] = t_;                                     \
      }                                                                     \
  }while(0)
#define BAR()   asm volatile("s_barrier" ::: "memory")
#define LGK0()  do{ asm volatile("s_waitcnt lgkmcnt(0)" ::: "memory"); \
                    __builtin_amdgcn_sched_barrier(0); }while(0)

  const int T = K >> 6;
  // prologue: t0 all 4 halves FIRST, then t1's B0,A0 (gate math depends on order)
  STAGE_A(0,0); STAGE_A(0,1); STAGE_B(0,0); STAGE_B(0,1);
  STAGE_B(1,0); STAGE_A(1,0);
  asm volatile("s_waitcnt vmcnt(4)" ::: "memory");   // t0's 8 loads arrived
  BAR();

  for(int tk=0; tk<T; tk++){
    const int aSlot = ((tk&1)*2 + aHalfSel)*16384;
    const int bSlot = 65536 + ((tk&1)*2 + bHalfSel)*16384;
    // ---- ph0: A(qm0)+B(qn0); stage B(t+1,1) ----
    RD_A(0); RD_B(0);
    if(tk+1 < T) STAGE_B(tk+1, 1);
    BAR(); LGK0();
    __builtin_amdgcn_s_setprio(1); MM(0,0); __builtin_amdgcn_s_setprio(0);
    BAR();
    // ---- ph1: B(qn1); stage A(t+1,1) ----
    RD_B(1);
    if(tk+1 < T) STAGE_A(tk+1, 1);
    BAR(); LGK0();
    __builtin_amdgcn_s_setprio(1); MM(0,1); __builtin_amdgcn_s_setprio(0);
    BAR();
    // ---- ph2: A(qm1); stage B(t+2,0) ----
    RD_A(1);
    if(tk+2 < T) STAGE_B(tk+2, 0);
    BAR(); LGK0();
    __builtin_amdgcn_s_setprio(1); MM(1,0); __builtin_amdgcn_s_setprio(0);
    BAR();
    // ---- ph3: regs only; stage A(t+2,0); vmcnt gate for next tile ----
    if(tk+2 < T) STAGE_A(tk+2, 0);
    if(tk+1 < T){
      if(tk+2 < T) asm volatile("s_waitcnt vmcnt(4)" ::: "memory");
      else         asm volatile("s_waitcnt vmcnt(0)" ::: "memory");
    }
    BAR();
    __builtin_amdgcn_s_setprio(1); MM(1,1); __builtin_amdgcn_s_setprio(0);
    BAR();
  }
#undef RD_A
#undef RD_B
#undef MM
#undef STAGE_A
#undef STAGE_B

  const float dsc = scalePtr ? scalePtr[z] : 1.0f;
  const long long cBase = (long long)zq*zC1 + (long long)zr*zC2;
  const int r4 = (lane>>4)*4;
#pragma unroll
  for(int mf=0; mf<8; mf++){
    const int row0 = m0 + wm*128 + mf*16 + r4;
#pragma unroll
    for(int nf=0; nf<4; nf++){
      const int col = n0 + wn*64 + nf*16 + l15;
      if(col < Ncols){
#pragma unroll
        for(int r=0;r<4;r++){
          const int row = row0 + r;
          if(row < M){
            float v = acc[mf][nf][r];
            if(bias1) v += bias1[col];
            v *= hscale * dsc;
            if(bias2) v += bias2[(row/rowsPerB)*b2s + col];
            if(OUT_F32) ((float*)Cm)[cBase + (long long)row*sC + col] = v;
            else        ((u16*) Cm)[cBase + (long long)row*sC + col] = f2b(v);
          }
        }
      }
    }
  }
}

// ---------------------------------------------------------------------------
// 256x128 4-wave 2-phase GEMM (r11 v7) kept for the small KV-proj grid.
// ---------------------------------------------------------------------------
template<int OUT_F32>
__global__ __launch_bounds__(256, 2)
void gemm128(const u16* __restrict__ A, const u16* __restrict__ Bm, void* __restrict__ Cm,
             int M, int Ncols, int K, int sA, int sB, int sC, int zdiv,
             long long zA1, long long zA2, long long zB1, long long zB2,
             long long zC1, long long zC2,
             const float* __restrict__ bias1, float hscale,
             const float* __restrict__ scalePtr,
             const float* __restrict__ bias2, int rowsPerB, int b2s,
             int mp, int np)
{
  __shared__ u16 lds[36864];
  int bx, by, z;
  if(mp > 0){ order_panel(mp, np, bx, by); z = 0; }
  else      { order_byinner(bx, by, z); }
  const int zq = z / zdiv, zr = z % zdiv;
  const u16* Ab = A  + (long long)zq*zA1 + (long long)zr*zA2;
  const u16* Bb = Bm + (long long)zq*zB1 + (long long)zr*zB2;
  const int m0 = bx*256, n0 = by*128;
  const int t = threadIdx.x, w = t>>6, lane = t&63;
  const int wm = w>>1, wn = w&1;
  const int l15 = lane & 15;

  const int srow = t>>2;
  const int scol = (((t&3) ^ ((srow>>1)&3)) << 3);
  const u16* aS = Ab + (long long)(m0 + srow)*sA + scol;
  const u16* bS = Bb + (long long)(n0 + srow)*sB + scol;
  const long long sA64 = (long long)64*sA, sB64 = (long long)64*sB;
  const int w512 = w*512;

#define STAGE(jt, buf) do{                                        \
    const u16* a0_ = aS + (long long)(jt)*32;                     \
    const u16* b0_ = bS + (long long)(jt)*32;                     \
    u16* la_ = lds + (buf)*8192 + w512;                           \
    u16* lb_ = lds + 24576 + (buf)*4096 + w512;                   \
    GLD16(a0_,          la_);                                     \
    GLD16(a0_ +   sA64, la_ + 2048);                              \
    GLD16(a0_ + 2*sA64, la_ + 4096);                              \
    GLD16(a0_ + 3*sA64, la_ + 6144);                              \
    GLD16(b0_,          lb_);                                     \
    GLD16(b0_ +   sB64, lb_ + 2048);                              \
  }while(0)

  f32x4 acc[8][4];
#pragma unroll
  for(int i=0;i<8;i++)
#pragma unroll
    for(int j=0;j<4;j++) acc[i][j] = (f32x4)(0.0f);

  const char* ldsc = (const char*)lds;
  const int ck = (((lane>>4) ^ ((lane>>1)&3)) << 4);
  const int aRowB = (wm*128 + l15) * 64;
  const int bRowB = (wn*64  + l15) * 64;

  const int T = K >> 5;
  STAGE(0, 0);
  STAGE(1, 1);

  int buf = 0;
  for(int j=0; j<T; j++){
    if(j == T-1) asm volatile("s_waitcnt vmcnt(0)" ::: "memory");
    else         asm volatile("s_waitcnt vmcnt(6)" ::: "memory");
    asm volatile("s_barrier" ::: "memory");

    const int aBuf = buf*16384 + aRowB;
    const int bBuf = 49152 + buf*8192 + bRowB;
    bf16x8 af[8], bfv[4];
#pragma unroll
    for(int fr=0; fr<8; fr++) af[fr]  = *(const bf16x8*)(ldsc + aBuf + fr*1024 + ck);
#pragma unroll
    for(int fn=0; fn<4; fn++) bfv[fn] = *(const bf16x8*)(ldsc + bBuf + fn*1024 + ck);
    {
      const int nbuf = (buf+2 >= 3) ? buf-1 : buf+2;
      if(j+2 < T) STAGE(j+2, nbuf);
    }
    __builtin_amdgcn_s_setprio(1);
#pragma unroll
    for(int fr=0; fr<8; fr++)
#pragma unroll
      for(int fn=0; fn<4; fn++)
        acc[fr][fn] = __builtin_amdgcn_mfma_f32_16x16x32_bf16(af[fr], bfv[fn], acc[fr][fn], 0,0,0);
    __builtin_amdgcn_s_setprio(0);
    buf = (buf+1 >= 3) ? 0 : buf+1;
  }
#undef STAGE

  const float dsc = scalePtr ? scalePtr[z] : 1.0f;
  const long long cBase = (long long)zq*zC1 + (long long)zr*zC2;
  const int r4 = (lane>>4)*4;
#pragma unroll
  for(int mf=0; mf<8; mf++){
    const int row0 = m0 + wm*128 + mf*16 + r4;
#pragma unroll
    for(int nf=0; nf<4; nf++){
      const int col = n0 + wn*64 + nf*16 + l15;
      if(col < Ncols){
#pragma unroll
        for(int r=0;r<4;r++){
          const int row = row0 + r;
          if(row < M){
            float v = acc[mf][nf][r];
            if(bias1) v += bias1[col];
            v *= hscale * dsc;
            if(bias2) v += bias2[(row/rowsPerB)*b2s + col];
            if(OUT_F32) ((float*)Cm)[cBase + (long long)row*sC + col] = v;
            else        ((u16*) Cm)[cBase + (long long)row*sC + col] = f2b(v);
          }
        }
      }
    }
  }
}

// f32 (K,N) weight -> bf16 (N,K) transpose
__global__ __launch_bounds__(256)
void wt_kernel(const float* __restrict__ W, u16* __restrict__ Wt, int K, int N){
  __shared__ float tile[32][33];
  const int n0 = blockIdx.x*32, k0 = blockIdx.y*32;
  const int t = threadIdx.x, tr = t>>5, tc = t&31;
#pragma unroll
  for(int i=0;i<4;i++)
    tile[tr+i*8][tc] = W[(long long)(k0+tr+i*8)*N + n0+tc];
  __syncthreads();
#pragma unroll
  for(int i=0;i<4;i++)
    Wt[(long long)(n0+tr+i*8)*K + k0+tc] = f2b(tile[tc][tr+i*8]);
}

__global__ __launch_bounds__(256)
void cvt_bf16(const float* __restrict__ in, u16* __restrict__ outp, long long n){
  long long i = ((long long)blockIdx.x*256 + threadIdx.x)*4;
  if(i+3 < n){
    float4 v = *(const float4*)(in+i);
    ushort4 o; o.x=f2b(v.x); o.y=f2b(v.y); o.z=f2b(v.z); o.w=f2b(v.w);
    *(ushort4*)(outp+i) = o;
  }
}

// depthwise 3x3 stride-2 SAME conv (pad lo=0,hi=1) + bias + LayerNorm -> bf16
__global__ __launch_bounds__(256)
void conv_ln(const float* __restrict__ q, const float* __restrict__ ker,
             const float* __restrict__ cbias, const float* __restrict__ gamma,
             const float* __restrict__ beta, u16* __restrict__ xo)
{
  const int p = blockIdx.x;
  const int b = p / 784, pix = p % 784;
  const int oy = pix / 28, ox = pix % 28;
  const int t = threadIdx.x;
  __shared__ float red[256];
  float v[2];
#pragma unroll
  for(int e=0;e<2;e++){
    const int c = t + e*256;
    float acc = cbias[c];
    for(int ky=0;ky<3;ky++){
      const int y = oy*2 + ky;
      if(y >= HIMG) continue;
      for(int kx=0;kx<3;kx++){
        const int x = ox*2 + kx;
        if(x >= WIMG) continue;
        acc += q[(((long long)b*HIMG + y)*WIMG + x)*C_ + c] * ker[(ky*3+kx)*C_ + c];
      }
    }
    v[e] = acc;
  }
  red[t]=v[0]+v[1]; __syncthreads();
  for(int st=128; st>0; st>>=1){ if(t<st) red[t]+=red[t+st]; __syncthreads(); }
  const float mu = red[0] * (1.0f/C_);
  __syncthreads();
  const float d0=v[0]-mu, d1=v[1]-mu;
  red[t]=d0*d0+d1*d1; __syncthreads();
  for(int st=128; st>0; st>>=1){ if(t<st) red[t]+=red[t+st]; __syncthreads(); }
  const float rs = rsqrtf(red[0]*(1.0f/C_) + 1e-3f);
  const long long ob = (long long)p*C_;
#pragma unroll
  for(int e=0;e<2;e++){
    const int c = t+e*256;
    xo[ob+c] = f2b((v[e]-mu)*rs*gamma[c] + beta[c]);
  }
}

// per-batch: V part of KV_b (784 x 4096, row stride sV) -> Vt_b (4096,896), k zero-padded
__global__ __launch_bounds__(256)
void vt_kernel(const u16* __restrict__ Vf_b, u16* __restrict__ Vt_b, int sV){
  __shared__ u16 tile[32][33];
  const int k0 = blockIdx.x*32, d0 = blockIdx.y*32;
  const int t = threadIdx.x, tr = t>>5, tc = t&31;
#pragma unroll
  for(int i=0;i<4;i++){
    const int k = k0+tr+i*8;
    tile[tr+i*8][tc] = (k < NK_) ? Vf_b[(long long)k*sV + d0+tc] : (u16)0;
  }
  __syncthreads();
#pragma unroll
  for(int i=0;i<4;i++)
    Vt_b[(long long)(d0+tr+i*8)*NKP_ + k0+tc] = tile[tc][tr+i*8];
}

// ---------------------------------------------------------------------------
// Wave-parallel mix+softmax: one block (512 thr = 8 waves) per q-row.
// Unique-slot partial sums. Zeroes pad cols 784..895.
// ---------------------------------------------------------------------------
__global__ __launch_bounds__(512)
void mix_softmax(u16* __restrict__ S_b, const float* __restrict__ tw,
                 float* __restrict__ partial_b)
{
  const int qi = blockIdx.x;
  const int t = threadIdx.x;
  const int wave = t >> 6, lane = t & 63;
  __shared__ float sv[8*NK_];
  const long long rowstr = (long long)NQ_*NKP_;
  const long long base = (long long)qi*NKP_;

  for(int idx = t; idx < 8*196; idx += 512){
    const int h = idx / 196, c4 = idx % 196;
    ushort4 u4 = *(const ushort4*)(S_b + base + h*rowstr + c4*4);
    float* d = sv + h*NK_ + c4*4;
    d[0]=b2f(u4.x); d[1]=b2f(u4.y); d[2]=b2f(u4.z); d[3]=b2f(u4.w);
  }
  __syncthreads();

  const int g = wave;
  float wgt[8];
#pragma unroll
  for(int h=0;h<8;h++) wgt[h] = tw[h*8+g];

  float xs[13];
  float lmax = -1e30f;
#pragma unroll
  for(int j=0;j<13;j++){
    const int k = j*64 + lane;
    if(k < NK_){
      float x = 0.f;
#pragma unroll
      for(int h=0;h<8;h++) x += wgt[h]*sv[h*NK_+k];
      xs[j] = x;
      lmax = fmaxf(lmax, x);
    } else xs[j] = -1e30f;
  }
#pragma unroll
  for(int off=32; off>=1; off>>=1) lmax = fmaxf(lmax, __shfl_xor(lmax, off));

  float lsum = 0.f;
#pragma unroll
  for(int j=0;j<13;j++){
    const int k = j*64 + lane;
    if(k < NK_){
      const float e = __expf(xs[j] - lmax);
      xs[j] = e; lsum += e;
    }
  }
#pragma unroll
  for(int off=32; off>=1; off>>=1) lsum += __shfl_xor(lsum, off);
  const float inv = 1.0f/lsum;

  u16* dst = S_b + base + g*rowstr;
  float lss = 0.f;
#pragma unroll
  for(int j=0;j<13;j++){
    const int k = j*64 + lane;
    if(k < NK_){
      const float dev = xs[j]*inv - (1.0f/NK_);
      dst[k] = f2b(dev);
      lss += dev*dev;
    }
  }
  for(int k = NK_ + lane; k < NKP_; k += 64) dst[k] = 0;
#pragma unroll
  for(int off=32; off>=1; off>>=1) lss += __shfl_xor(lss, off);
  if(lane==0) partial_b[g*NQ_ + qi] = lss;
}

// column sums of V, k-split into 8 chunks of 98 -> part[kc][hd]
__global__ __launch_bounds__(256)
void colsum_v(const u16* __restrict__ Vf_b, float* __restrict__ part, int sV){
  const int hd = blockIdx.x*256 + threadIdx.x;
  const int kc = blockIdx.y;
  const u16* p = Vf_b + (long long)kc*98*sV + hd;
  float s=0.f;
  for(int k=0;k<98;k++) s += b2f(p[(long long)k*sV]);
  part[(long long)kc*HD_ + hd] = s;
}

__global__ __launch_bounds__(256)
void finalize_stats(const float* __restrict__ partial_b, const float* __restrict__ bng_b,
                    const float* __restrict__ bnb_b, float* __restrict__ a_b,
                    float* __restrict__ c_b){
  const int g = blockIdx.x;
  const int t = threadIdx.x;
  __shared__ float red[4];
  float s = 0.f;
  for(int i=t; i<NQ_; i+=256) s += partial_b[g*NQ_ + i];
#pragma unroll
  for(int off=32; off>=1; off>>=1) s += __shfl_xor(s, off);
  if((t&63)==0) red[t>>6] = s;
  __syncthreads();
  if(t==0){
    const float tot = red[0]+red[1]+red[2]+red[3];
    const float s2 = tot * (1.0f/((float)NQ_*(float)NK_));
    a_b[g] = bng_b[g]*rsqrtf(s2 + 1e-3f);
    c_b[g] = bnb_b[g];
  }
}

// corr_b[n] = sum_g c_b[g] * (colsumV_b[g*512:(g+1)*512] . Wo_g[:,n]); colsum k-split
__global__ __launch_bounds__(256)
void corr_kernel(const float* __restrict__ part, const u16* __restrict__ Wot,
                 const float* __restrict__ c_b, float* __restrict__ corr_b){
  const int n = blockIdx.x, t = threadIdx.x;
  __shared__ float red[256];
  float s = 0.f;
  for(int hd=t; hd<HD_; hd+=256){
    float cs = 0.f;
#pragma unroll
    for(int kc=0; kc<8; kc++) cs += part[(long long)kc*HD_ + hd];
    s += c_b[hd>>9] * cs * b2f(Wot[(long long)n*HD_+hd]);
  }
  red[t]=s; __syncthreads();
  for(int st=128; st>0; st>>=1){ if(t<st) red[t]+=red[t+st]; __syncthreads(); }
  if(t==0) corr_b[n]=red[0];
}

// ---------------------------------------------------------------------------
extern "C" void kernel_launch(void* const* d_in, const int* in_sizes, int n_in,
                              void* d_out, int out_size, void* d_ws, size_t ws_size,
                              hipStream_t stream)
{
  (void)in_sizes; (void)n_in; (void)out_size;
  const float* queries = (const float*)d_in[0];
  const float* Wq  = (const float*)d_in[3];
  const float* bq  = (const float*)d_in[4];
  const float* Wk  = (const float*)d_in[5];
  const float* bk  = (const float*)d_in[6];
  const float* Wv  = (const float*)d_in[7];
  const float* bv  = (const float*)d_in[8];
  const float* Wo  = (const float*)d_in[9];
  const float* bo  = (const float*)d_in[10];
  const float* srk = (const float*)d_in[11];
  const float* srb = (const float*)d_in[12];
  const float* lng = (const float*)d_in[13];
  const float* lnb = (const float*)d_in[14];
  const float* tw  = (const float*)d_in[15];
  const float* bng = (const float*)d_in[17];
  const float* bnb = (const float*)d_in[18];
  float* out = (float*)d_out;
  const float QSC = 0.04419417382415922f;   // 1/sqrt(512)

  char* w = (char*)d_ws;
  size_t off = 0;
  auto alloc = [&](size_t bytes)->char*{
    char* p = w + off; off += (bytes + 255) & ~(size_t)255; return p;
  };

  const bool tierA = (ws_size >= (size_t)210*1024*1024);

  u16* Wqt = (u16*)alloc((size_t)HD_*C_*2);
  u16* Wkt = (u16*)alloc((size_t)HD_*C_*2);   // Wvt follows contiguously
  u16* Wvt = (u16*)alloc((size_t)HD_*C_*2);
  u16* Wot = (u16*)alloc((size_t)C_*HD_*2);
  u16* x   = (u16*)alloc((size_t)B_*NK_*C_*2 + 262144);
  float* bkv = (float*)alloc((size_t)2*HD_*4);
  u16* Qin;
  u16* QfU;
  if(tierA){
    Qin = (u16*)alloc((size_t)B_*NQ_*C_*2);
    QfU = (u16*)alloc((size_t)B_*NQ_*HD_*2 + 2097152);      // +2M: score A over-read
  } else {
    Qin = (u16*)alloc((size_t)NQ_*C_*2 + 262144);
    QfU = (u16*)alloc((size_t)NQ_*HD_*2 + 2097152);
  }
  u16* KV_b = (u16*)alloc((size_t)NK_*2*HD_*2 + 4194304);   // +4M: score B over-read (240 rows)
  u16* Vt_b = (u16*)alloc((size_t)HD_*NKP_*2);
  u16* S_b  = (u16*)alloc((size_t)8*NQ_*NKP_*2 + 524288);   // +512K: PV A over-read
  float* colsum  = (float*)alloc((size_t)8*HD_*4);
  float* partial = (float*)alloc((size_t)8*NQ_*4);
  float* aArr    = (float*)alloc(256);
  float* cArr    = (float*)alloc(256);
  float* corrB   = (float*)alloc((size_t)B_*C_*4);

  // ---- weight prep + conv+LN ----
  wt_kernel<<<dim3(128,16), 256, 0, stream>>>(Wq, Wqt, 512, 4096);
  wt_kernel<<<dim3(128,16), 256, 0, stream>>>(Wk, Wkt, 512, 4096);
  wt_kernel<<<dim3(128,16), 256, 0, stream>>>(Wv, Wvt, 512, 4096);
  wt_kernel<<<dim3(16,128), 256, 0, stream>>>(Wo, Wot, 4096, 512);
  conv_ln<<<B_*NK_, 256, 0, stream>>>(queries, srk, srb, lng, lnb, x);
  hipMemcpyAsync(bkv,      bk, HD_*4, hipMemcpyDeviceToDevice, stream);
  hipMemcpyAsync(bkv+HD_,  bv, HD_*4, hipMemcpyDeviceToDevice, stream);

  if(tierA){
    cvt_bf16<<<6272, 256, 0, stream>>>(queries, Qin, (long long)B_*NQ_*C_);
    // Qf = (queries@Wq + bq)/sqrt(512): 8-phase template, panel order 4x2
    gemm8p<0><<<dim3(49,16,1),512,0,stream>>>(Qin, Wqt, QfU, B_*NQ_, 4096, 512,
        512, 512, HD_, 1, 0,0,0,0,0,0, bq, QSC, nullptr, nullptr, 1, 0, 4, 2);
  }

  for(int b=0; b<B_; b++){
    u16* Qf_b = tierA ? (QfU + (size_t)b*NQ_*HD_) : QfU;
    if(!tierA){
      cvt_bf16<<<1568, 256, 0, stream>>>(queries + (size_t)b*NQ_*C_, Qin, (long long)NQ_*C_);
      gemm8p<0><<<dim3(13,16,1),512,0,stream>>>(Qin, Wqt, Qf_b, NQ_, 4096, 512,
          512, 512, HD_, 1, 0,0,0,0,0,0, bq, QSC, nullptr, nullptr, 1, 0, 4, 2);
    }
    const u16* x_b = x + (size_t)b*NK_*C_;
    // combined K|V projection (small grid -> 2-phase kernel)
    gemm128<0><<<dim3(4,64,1),256,0,stream>>>(x_b, Wkt, KV_b, NK_, 2*HD_, 512,
        512, 512, 2*HD_, 1, 0,0,0,0,0,0, bkv, 1.0f, nullptr, nullptr, 1, 0, 0, 0);
    vt_kernel<<<dim3(28,128),256,0,stream>>>(KV_b + HD_, Vt_b, 2*HD_);
    colsum_v<<<dim3(16,8),256,0,stream>>>(KV_b + HD_, colsum, 2*HD_);
    // per-head scores: S_b[z] = Qf_b[:, z*512:+512] @ K_b[:, z*512:+512]^T
    gemm8p<0><<<dim3(13,4,8),512,0,stream>>>(Qf_b, KV_b, S_b, NQ_, NKP_, 512,
        HD_, 2*HD_, NKP_, 8, 0, 512, 0, 512, 0, (long long)NQ_*NKP_,
        nullptr, 1.0f, nullptr, nullptr, 1, 0, 0, 0);
    mix_softmax<<<NQ_, 512, 0, stream>>>(S_b, tw, partial);
    finalize_stats<<<8,256,0,stream>>>(partial, bng + b*8, bnb + b*8, aArr + b*8, cArr + b*8);
    corr_kernel<<<512,256,0,stream>>>(colsum, Wot, cArr + b*8, corrB + b*C_);
    // U_b[:, z*512+d] = a[b,z] * (P~_z @ V_z)   (K=896 -> T=14 tiles)
    gemm8p<0><<<dim3(13,2,8),512,0,stream>>>(S_b, Vt_b, Qf_b, NQ_, 512, NKP_,
        NKP_, NKP_, HD_, 8, 0, (long long)NQ_*NKP_, 0, (long long)512*NKP_, 0, 512,
        nullptr, 1.0f, aArr + b*8, nullptr, 1, 0, 0, 0);
    if(!tierA){
      gemm8p<1><<<dim3(13,2,1),512,0,stream>>>(Qf_b, Wot, out + (size_t)b*NQ_*C_,
          NQ_, 512, HD_, HD_, HD_, C_,
          1, 0,0,0,0,0,0, bo, 1.0f, nullptr, corrB + b*C_, NQ_, C_, 0, 0);
    }
  }

  if(tierA){
    // out = U @ Wo + bo + corr[b,:]  (K=4096 -> T=64: deep pipeline)
    gemm8p<1><<<dim3(49,2,1),512,0,stream>>>(QfU, Wot, out, B_*NQ_, 512, HD_,
        HD_, HD_, C_, 1, 0,0,0,0,0,0, bo, 1.0f, nullptr, corrB, NQ_, C_, 0, 0);
  }
}

// Round 14
// 969.876 us; speedup vs baseline: 1.1173x; 1.0806x over previous
//
#include <hip/hip_runtime.h>
#include <hip/hip_bf16.h>
#include <math.h>

typedef unsigned short u16;
typedef __attribute__((ext_vector_type(4))) float f32x4;
typedef __attribute__((ext_vector_type(8))) __bf16 bf16x8;

#define B_    4
#define NQ_   3136
#define C_    512
#define HIMG  56
#define WIMG  56
#define HD_   4096
#define NK_   784
#define SLAB  800          // per-head k-slab width (K%32==0), cols 784..799 zero
#define SROW  6400         // S row stride = 8*SLAB

static __device__ __forceinline__ float b2f(u16 u){
  union { unsigned int i; float f; } v; v.i = ((unsigned int)u)<<16; return v.f;
}
static __device__ __forceinline__ u16 f2b(float f){
  union { float f; unsigned int i; } v; v.f = f;
  unsigned int r = v.i + 0x7fffu + ((v.i>>16)&1u);
  return (u16)(r>>16);
}

#define GLD16(gsrc, ldst) __builtin_amdgcn_global_load_lds( \
    (const __attribute__((address_space(1))) void*)(gsrc), \
    (__attribute__((address_space(3))) void*)(ldst), 16, 0, 0)

// ---------------------------------------------------------------------------
// m204-bijective by-inner block order (XCD = linear_id%8 round-robin):
// consecutive ranks on one XCD share bx and one z slice -> L2 panel reuse.
// ---------------------------------------------------------------------------
static __device__ __forceinline__ void order_byinner(int &bx, int &by, int &bz){
  const int nx = gridDim.x, ny = gridDim.y, nz = gridDim.z;
  const long l = blockIdx.x + (long)nx*(blockIdx.y + (long)ny*blockIdx.z);
  const long n = (long)nx*ny*nz;
  const long q8 = n>>3, r8 = n&7;
  const long xcd = l&7, idx = l>>3;
  long g = (xcd<r8 ? xcd*(q8+1) : r8*(q8+1) + (xcd-r8)*q8) + idx;
  by = (int)(g % ny); g /= ny;
  bx = (int)(g % nx);
  bz = (int)(g / nx);
}

// ---------------------------------------------------------------------------
// 256x128 4-wave 2-phase bf16 GEMM (r11 v7, proven best: 0 conflicts, 48MB
// fetch with panel reuse). BK=32, 3-buffer ring, depth-2 prefetch, counted
// vmcnt(6), 72 KiB LDS -> 2 blocks/CU, XOR swizzle chunk^=(row>>1)&3.
// C[m,n] = (sum_k A[m,k]*B[n,k] + bias1[n]) * hscale * scalePtr[z] (+bias2).
// Loads NOT masked (caller guarantees over-read slack, finite data);
// stores masked by row<M && col<Ncols. Requires K%32==0, K>=64.
// ---------------------------------------------------------------------------
template<int OUT_F32>
__global__ __launch_bounds__(256, 2)
void gemm128(const u16* __restrict__ A, const u16* __restrict__ Bm, void* __restrict__ Cm,
             int M, int Ncols, int K, int sA, int sB, int sC, int zdiv,
             long long zA1, long long zA2, long long zB1, long long zB2,
             long long zC1, long long zC2,
             const float* __restrict__ bias1, float hscale,
             const float* __restrict__ scalePtr,
             const float* __restrict__ bias2, int rowsPerB, int b2s)
{
  __shared__ u16 lds[36864];
  int bx, by, z;
  order_byinner(bx, by, z);
  const int zq = z / zdiv, zr = z % zdiv;
  const u16* Ab = A  + (long long)zq*zA1 + (long long)zr*zA2;
  const u16* Bb = Bm + (long long)zq*zB1 + (long long)zr*zB2;
  const int m0 = bx*256, n0 = by*128;
  const int t = threadIdx.x, w = t>>6, lane = t&63;
  const int wm = w>>1, wn = w&1;
  const int l15 = lane & 15;

  const int srow = t>>2;
  const int scol = (((t&3) ^ ((srow>>1)&3)) << 3);
  const u16* aS = Ab + (long long)(m0 + srow)*sA + scol;
  const u16* bS = Bb + (long long)(n0 + srow)*sB + scol;
  const long long sA64 = (long long)64*sA, sB64 = (long long)64*sB;
  const int w512 = w*512;

#define STAGE(jt, buf) do{                                        \
    const u16* a0_ = aS + (long long)(jt)*32;                     \
    const u16* b0_ = bS + (long long)(jt)*32;                     \
    u16* la_ = lds + (buf)*8192 + w512;                           \
    u16* lb_ = lds + 24576 + (buf)*4096 + w512;                   \
    GLD16(a0_,          la_);                                     \
    GLD16(a0_ +   sA64, la_ + 2048);                              \
    GLD16(a0_ + 2*sA64, la_ + 4096);                              \
    GLD16(a0_ + 3*sA64, la_ + 6144);                              \
    GLD16(b0_,          lb_);                                     \
    GLD16(b0_ +   sB64, lb_ + 2048);                              \
  }while(0)

  f32x4 acc[8][4];
#pragma unroll
  for(int i=0;i<8;i++)
#pragma unroll
    for(int j=0;j<4;j++) acc[i][j] = (f32x4)(0.0f);

  const char* ldsc = (const char*)lds;
  const int ck = (((lane>>4) ^ ((lane>>1)&3)) << 4);
  const int aRowB = (wm*128 + l15) * 64;
  const int bRowB = (wn*64  + l15) * 64;

  const int T = K >> 5;
  STAGE(0, 0);
  STAGE(1, 1);

  int buf = 0;
  for(int j=0; j<T; j++){
    if(j == T-1) asm volatile("s_waitcnt vmcnt(0)" ::: "memory");
    else         asm volatile("s_waitcnt vmcnt(6)" ::: "memory");
    asm volatile("s_barrier" ::: "memory");

    const int aBuf = buf*16384 + aRowB;
    const int bBuf = 49152 + buf*8192 + bRowB;
    bf16x8 af[8], bfv[4];
#pragma unroll
    for(int fr=0; fr<8; fr++) af[fr]  = *(const bf16x8*)(ldsc + aBuf + fr*1024 + ck);
#pragma unroll
    for(int fn=0; fn<4; fn++) bfv[fn] = *(const bf16x8*)(ldsc + bBuf + fn*1024 + ck);
    {
      const int nbuf = (buf+2 >= 3) ? buf-1 : buf+2;
      if(j+2 < T) STAGE(j+2, nbuf);
    }
    __builtin_amdgcn_s_setprio(1);
#pragma unroll
    for(int fr=0; fr<8; fr++)
#pragma unroll
      for(int fn=0; fn<4; fn++)
        acc[fr][fn] = __builtin_amdgcn_mfma_f32_16x16x32_bf16(af[fr], bfv[fn], acc[fr][fn], 0,0,0);
    __builtin_amdgcn_s_setprio(0);
    buf = (buf+1 >= 3) ? 0 : buf+1;
  }
#undef STAGE

  const float dsc = scalePtr ? scalePtr[z] : 1.0f;
  const long long cBase = (long long)zq*zC1 + (long long)zr*zC2;
  const int r4 = (lane>>4)*4;
#pragma unroll
  for(int mf=0; mf<8; mf++){
    const int row0 = m0 + wm*128 + mf*16 + r4;
#pragma unroll
    for(int nf=0; nf<4; nf++){
      const int col = n0 + wn*64 + nf*16 + l15;
      if(col < Ncols){
#pragma unroll
        for(int r=0;r<4;r++){
          const int row = row0 + r;
          if(row < M){
            float v = acc[mf][nf][r];
            if(bias1) v += bias1[col];
            v *= hscale * dsc;
            if(bias2) v += bias2[(row/rowsPerB)*b2s + col];
            if(OUT_F32) ((float*)Cm)[cBase + (long long)row*sC + col] = v;
            else        ((u16*) Cm)[cBase + (long long)row*sC + col] = f2b(v);
          }
        }
      }
    }
  }
}

// f32 (K,N) weight -> bf16 (N,K) transpose
__global__ __launch_bounds__(256)
void wt_kernel(const float* __restrict__ W, u16* __restrict__ Wt, int K, int N){
  __shared__ float tile[32][33];
  const int n0 = blockIdx.x*32, k0 = blockIdx.y*32;
  const int t = threadIdx.x, tr = t>>5, tc = t&31;
#pragma unroll
  for(int i=0;i<4;i++)
    tile[tr+i*8][tc] = W[(long long)(k0+tr+i*8)*N + n0+tc];
  __syncthreads();
#pragma unroll
  for(int i=0;i<4;i++)
    Wt[(long long)(n0+tr+i*8)*K + k0+tc] = f2b(tile[tc][tr+i*8]);
}

__global__ __launch_bounds__(256)
void cvt_bf16(const float* __restrict__ in, u16* __restrict__ outp, long long n){
  long long i = ((long long)blockIdx.x*256 + threadIdx.x)*4;
  if(i+3 < n){
    float4 v = *(const float4*)(in+i);
    ushort4 o; o.x=f2b(v.x); o.y=f2b(v.y); o.z=f2b(v.z); o.w=f2b(v.w);
    *(ushort4*)(outp+i) = o;
  }
}

// depthwise 3x3 stride-2 SAME conv (pad lo=0,hi=1) + bias + LayerNorm -> bf16
__global__ __launch_bounds__(256)
void conv_ln(const float* __restrict__ q, const float* __restrict__ ker,
             const float* __restrict__ cbias, const float* __restrict__ gamma,
             const float* __restrict__ beta, u16* __restrict__ xo)
{
  const int p = blockIdx.x;
  const int b = p / 784, pix = p % 784;
  const int oy = pix / 28, ox = pix % 28;
  const int t = threadIdx.x;
  __shared__ float red[256];
  float v[2];
#pragma unroll
  for(int e=0;e<2;e++){
    const int c = t + e*256;
    float acc = cbias[c];
    for(int ky=0;ky<3;ky++){
      const int y = oy*2 + ky;
      if(y >= HIMG) continue;
      for(int kx=0;kx<3;kx++){
        const int x = ox*2 + kx;
        if(x >= WIMG) continue;
        acc += q[(((long long)b*HIMG + y)*WIMG + x)*C_ + c] * ker[(ky*3+kx)*C_ + c];
      }
    }
    v[e] = acc;
  }
  red[t]=v[0]+v[1]; __syncthreads();
  for(int st=128; st>0; st>>=1){ if(t<st) red[t]+=red[t+st]; __syncthreads(); }
  const float mu = red[0] * (1.0f/C_);
  __syncthreads();
  const float d0=v[0]-mu, d1=v[1]-mu;
  red[t]=d0*d0+d1*d1; __syncthreads();
  for(int st=128; st>0; st>>=1){ if(t<st) red[t]+=red[t+st]; __syncthreads(); }
  const float rs = rsqrtf(red[0]*(1.0f/C_) + 1e-3f);
  const long long ob = (long long)p*C_;
#pragma unroll
  for(int e=0;e<2;e++){
    const int c = t+e*256;
    xo[ob+c] = f2b((v[e]-mu)*rs*gamma[c] + beta[c]);
  }
}

// u[h*512+c] = QSC * sum_e Wk[c, h*512+e] * bq[h*512+e]   (f32 inputs)
__global__ __launch_bounds__(256)
void u_kernel(const float* __restrict__ Wk, const float* __restrict__ bq,
              float* __restrict__ u, float qsc){
  const int id = blockIdx.x*256 + threadIdx.x;   // 0..4095
  const int h = id >> 9, c = id & 511;
  float s = 0.f;
  for(int e=0; e<512; e++) s += Wk[(long long)c*HD_ + h*512 + e] * bq[h*512 + e];
  u[id] = s * qsc;
}

// r_b[h*784+k] = sum_c u[h*512+c] * x_b[k*512+c]
__global__ __launch_bounds__(256)
void r_kernel(const u16* __restrict__ x_b, const float* __restrict__ u,
              float* __restrict__ r_b){
  const int id = blockIdx.x*256 + threadIdx.x;
  if(id >= 8*NK_) return;
  const int h = id / NK_, k = id % NK_;
  float s = 0.f;
  for(int c=0; c<512; c++) s += u[h*512+c] * b2f(x_b[(long long)k*512 + c]);
  r_b[id] = s;
}

// cx[c] = sum_k x_b[k,c]
__global__ __launch_bounds__(256)
void cx_kernel(const u16* __restrict__ x_b, float* __restrict__ cx){
  const int c = blockIdx.x*256 + threadIdx.x;
  float s = 0.f;
  for(int k=0; k<NK_; k++) s += b2f(x_b[(long long)k*512 + c]);
  cx[c] = s;
}

// vv[e] = sum_c cx[c] * Wv[c, e]   (f32 Wv)
__global__ __launch_bounds__(256)
void vv_kernel(const float* __restrict__ cx, const float* __restrict__ Wv,
               float* __restrict__ vv){
  const int e = blockIdx.x*256 + threadIdx.x;
  float s = 0.f;
  for(int c=0; c<512; c++) s += cx[c] * Wv[(long long)c*HD_ + e];
  vv[e] = s;
}

// ---------------------------------------------------------------------------
// Wave-parallel mix+softmax, S layout [q][h*SLAB+k] (contiguous per row).
// Adds r_b[h*784+k] (bq@Wk^T@x term) before the head-mix. Writes deviations
// p - 1/784 bf16 back at [q][g*SLAB+k], zeros pad cols 784..799, unique-slot
// partial sums (no hot atomics).
// ---------------------------------------------------------------------------
__global__ __launch_bounds__(512)
void mix_softmax(u16* __restrict__ S_b, const float* __restrict__ tw,
                 const float* __restrict__ r_b, float* __restrict__ partial_b)
{
  const int qi = blockIdx.x;
  const int t = threadIdx.x;
  const int wave = t >> 6, lane = t & 63;
  __shared__ float sv[8*NK_];
  const long long base = (long long)qi*SROW;

  for(int idx = t; idx < 8*196; idx += 512){
    const int h = idx / 196, c4 = idx % 196;
    ushort4 u4 = *(const ushort4*)(S_b + base + h*SLAB + c4*4);
    float4 rv = *(const float4*)(r_b + h*NK_ + c4*4);
    float* d = sv + h*NK_ + c4*4;
    d[0]=b2f(u4.x)+rv.x; d[1]=b2f(u4.y)+rv.y;
    d[2]=b2f(u4.z)+rv.z; d[3]=b2f(u4.w)+rv.w;
  }
  __syncthreads();

  const int g = wave;
  float wgt[8];
#pragma unroll
  for(int h=0;h<8;h++) wgt[h] = tw[h*8+g];

  float xs[13];
  float lmax = -1e30f;
#pragma unroll
  for(int j=0;j<13;j++){
    const int k = j*64 + lane;
    if(k < NK_){
      float x = 0.f;
#pragma unroll
      for(int h=0;h<8;h++) x += wgt[h]*sv[h*NK_+k];
      xs[j] = x;
      lmax = fmaxf(lmax, x);
    } else xs[j] = -1e30f;
  }
#pragma unroll
  for(int off=32; off>=1; off>>=1) lmax = fmaxf(lmax, __shfl_xor(lmax, off));

  float lsum = 0.f;
#pragma unroll
  for(int j=0;j<13;j++){
    const int k = j*64 + lane;
    if(k < NK_){
      const float e = __expf(xs[j] - lmax);
      xs[j] = e; lsum += e;
    }
  }
#pragma unroll
  for(int off=32; off>=1; off>>=1) lsum += __shfl_xor(lsum, off);
  const float inv = 1.0f/lsum;

  u16* dst = S_b + base + g*SLAB;
  float lss = 0.f;
#pragma unroll
  for(int j=0;j<13;j++){
    const int k = j*64 + lane;
    if(k < NK_){
      const float dev = xs[j]*inv - (1.0f/NK_);
      dst[k] = f2b(dev);
      lss += dev*dev;
    }
  }
  if(lane < 16) dst[NK_ + lane] = 0;     // zero pad 784..799
#pragma unroll
  for(int off=32; off>=1; off>>=1) lss += __shfl_xor(lss, off);
  if(lane==0) partial_b[g*NQ_ + qi] = lss;
}

__global__ __launch_bounds__(256)
void finalize_stats(const float* __restrict__ partial_b, const float* __restrict__ bng_b,
                    const float* __restrict__ bnb_b, float* __restrict__ a_b,
                    float* __restrict__ c_b){
  const int g = blockIdx.x;
  const int t = threadIdx.x;
  __shared__ float red[4];
  float s = 0.f;
  for(int i=t; i<NQ_; i+=256) s += partial_b[g*NQ_ + i];
#pragma unroll
  for(int off=32; off>=1; off>>=1) s += __shfl_xor(s, off);
  if((t&63)==0) red[t>>6] = s;
  __syncthreads();
  if(t==0){
    const float tot = red[0]+red[1]+red[2]+red[3];
    const float s2 = tot * (1.0f/((float)NQ_*(float)NK_));   // m = 1/784 exact
    a_b[g] = bng_b[g]*rsqrtf(s2 + 1e-3f);
    c_b[g] = bnb_b[g];
  }
}

// corr_b[n] = sum_e c_b[e>>9] * (vv[e] + 784*bv[e]) * Wot[n,e]
__global__ __launch_bounds__(256)
void corr_kernel(const float* __restrict__ vv, const float* __restrict__ bv,
                 const u16* __restrict__ Wot, const float* __restrict__ c_b,
                 float* __restrict__ corr_b){
  const int n = blockIdx.x, t = threadIdx.x;
  __shared__ float red[256];
  float s = 0.f;
  for(int e=t; e<HD_; e+=256)
    s += c_b[e>>9] * (vv[e] + 784.0f*bv[e]) * b2f(Wot[(long long)n*HD_+e]);
  red[t]=s; __syncthreads();
  for(int st=128; st>0; st>>=1){ if(t<st) red[t]+=red[t+st]; __syncthreads(); }
  if(t==0) corr_b[n]=red[0];
}

// ---------------------------------------------------------------------------
extern "C" void kernel_launch(void* const* d_in, const int* in_sizes, int n_in,
                              void* d_out, int out_size, void* d_ws, size_t ws_size,
                              hipStream_t stream)
{
  (void)in_sizes; (void)n_in; (void)out_size; (void)ws_size;
  const float* queries = (const float*)d_in[0];
  const float* Wq  = (const float*)d_in[3];
  const float* bq  = (const float*)d_in[4];
  const float* Wk  = (const float*)d_in[5];
  // bk (d_in[6]): q-constant score term -> cancels in softmax exactly
  const float* Wv  = (const float*)d_in[7];
  const float* bv  = (const float*)d_in[8];
  const float* Wo  = (const float*)d_in[9];
  const float* bo  = (const float*)d_in[10];
  const float* srk = (const float*)d_in[11];
  const float* srb = (const float*)d_in[12];
  const float* lng = (const float*)d_in[13];
  const float* lnb = (const float*)d_in[14];
  const float* tw  = (const float*)d_in[15];
  const float* bng = (const float*)d_in[17];
  const float* bnb = (const float*)d_in[18];
  float* out = (float*)d_out;
  const float QSC = 0.04419417382415922f;   // 1/sqrt(512)

  char* w = (char*)d_ws;
  size_t off = 0;
  auto alloc = [&](size_t bytes)->char*{
    char* p = w + off; off += (bytes + 255) & ~(size_t)255; return p;
  };

  // ---- permanent buffers (~132 MB) ----
  u16* Wvt = (u16*)alloc((size_t)HD_*C_*2);                 // V weight, (4096,512) bf16
  u16* Wot = (u16*)alloc((size_t)C_*HD_*2);                 // out weight, (512,4096) bf16
  u16* Gt  = (u16*)alloc((size_t)8*C_*C_*2 + 262144);       // per-head Wq@Wk^T, [h][d][c]
  u16* x   = (u16*)alloc((size_t)B_*NK_*C_*2 + 262144);     // conv+LN output (+over-read pad)
  u16* Qin = (u16*)alloc((size_t)B_*NQ_*C_*2 + 262144);     // bf16 queries
  u16* U   = (u16*)alloc((size_t)B_*NQ_*HD_*2);             // PV output (exact-fit M)
  // ---- scratch region (~56 MB), multi-use ----
  char* scratch = alloc((size_t)56262656);
  u16* Wkc = (u16*)scratch;                                  // pre-loop only
  u16* Wqc = (u16*)(scratch + 4194304);                      // (covers Gt B over-read)
  u16* S_b  = (u16*)scratch;                                 // 3136 x 6400 (+2.5M pad)
  u16* Vt_b = (u16*)(scratch + 42762240);                    // 4096 x 800 (+0.25M pad)
  u16* H_b  = (u16*)(scratch + 49577984);                    // 8 x 784 x 512 (+0.25M pad)
  // ---- small buffers ----
  float* uArr    = (float*)alloc((size_t)HD_*4);
  float* rArr    = (float*)alloc((size_t)8*NK_*4);
  float* cx      = (float*)alloc((size_t)C_*4);
  float* vv      = (float*)alloc((size_t)HD_*4);
  float* partial = (float*)alloc((size_t)8*NQ_*4);
  float* aArr    = (float*)alloc(256);
  float* cArr    = (float*)alloc(256);
  float* corrB   = (float*)alloc((size_t)B_*C_*4);

  // ---- weight prep ----
  wt_kernel<<<dim3(128,16), 256, 0, stream>>>(Wv, Wvt, 512, 4096);
  wt_kernel<<<dim3(16,128), 256, 0, stream>>>(Wo, Wot, 4096, 512);
  cvt_bf16<<<2048, 256, 0, stream>>>(Wk, Wkc, (long long)C_*HD_);
  cvt_bf16<<<2048, 256, 0, stream>>>(Wq, Wqc, (long long)C_*HD_);
  cvt_bf16<<<6272, 256, 0, stream>>>(queries, Qin, (long long)B_*NQ_*C_);
  conv_ln<<<B_*NK_, 256, 0, stream>>>(queries, srk, srb, lng, lnb, x);
  u_kernel<<<16, 256, 0, stream>>>(Wk, bq, uArr, QSC);

  // Gt[h][d][c] = QSC * sum_e Wq[d,h512+e]*Wk[c,h512+e]
  gemm128<0><<<dim3(2,4,8),256,0,stream>>>(Wqc, Wkc, Gt, 512, 512, 512,
      HD_, HD_, 512, 8, 0, 512, 0, 512, 0, (long long)C_*C_,
      nullptr, QSC, nullptr, nullptr, 1, 0);

  for(int b=0; b<B_; b++){
    const u16* x_b = x + (size_t)b*NK_*C_;
    const u16* Qin_b = Qin + (size_t)b*NQ_*C_;
    u16* U_b = U + (size_t)b*NQ_*HD_;

    // H_b[h][k][d] = sum_c x_b[k,c] * Gt[h][d][c]
    gemm128<0><<<dim3(4,4,8),256,0,stream>>>(x_b, Gt, H_b, NK_, 512, 512,
        512, 512, 512, 8, 0, 0, 0, (long long)C_*C_, 0, (long long)NK_*512,
        nullptr, 1.0f, nullptr, nullptr, 1, 0);
    r_kernel<<<25, 256, 0, stream>>>(x_b, uArr, rArr);
    // scores: S_b[q][h*SLAB+k] = sum_d Qin_b[q,d] * H_b[h][k][d]
    gemm128<0><<<dim3(13,7,8),256,0,stream>>>(Qin_b, H_b, S_b, NQ_, NK_, 512,
        512, 512, SROW, 8, 0, 0, 0, (long long)NK_*512, 0, SLAB,
        nullptr, 1.0f, nullptr, nullptr, 1, 0);
    // Vt_b[d][k] = sum_c Wvt[d,c] * x_b[k,c]   (cols 784..799 garbage-finite,
    // harmless: PV's A has zeros there)
    gemm128<0><<<dim3(16,7,1),256,0,stream>>>(Wvt, x_b, Vt_b, HD_, NK_, 512,
        512, 512, SLAB, 1, 0,0,0,0,0,0, nullptr, 1.0f, nullptr, nullptr, 1, 0);
    cx_kernel<<<2, 256, 0, stream>>>(x_b, cx);
    vv_kernel<<<16, 256, 0, stream>>>(cx, Wv, vv);
    mix_softmax<<<NQ_, 512, 0, stream>>>(S_b, tw, rArr, partial);
    finalize_stats<<<8,256,0,stream>>>(partial, bng + b*8, bnb + b*8, aArr + b*8, cArr + b*8);
    corr_kernel<<<512,256,0,stream>>>(vv, bv, Wot, cArr + b*8, corrB + b*C_);
    // U_b[q][h*512+d] = a[b,h] * sum_k P~[q,h*SLAB+k] * Vt_b[h*512+d][k]
    gemm128<0><<<dim3(13,4,8),256,0,stream>>>(S_b, Vt_b, U_b, NQ_, 512, SLAB,
        SROW, SLAB, HD_, 8, 0, SLAB, 0, (long long)512*SLAB, 0, 512,
        nullptr, 1.0f, aArr + b*8, nullptr, 1, 0);
  }

  // out = U @ Wo + bo + corr[b,:]
  gemm128<1><<<dim3(49,4,1),256,0,stream>>>(U, Wot, out, B_*NQ_, 512, HD_,
      HD_, HD_, C_, 1, 0,0,0,0,0,0, bo, 1.0f, nullptr, corrB, NQ_, C_);
}